// Round 1
// baseline (468.611 us; speedup 1.0000x reference)
//
#include <hip/hip_runtime.h>
#include <hip/hip_bf16.h>
#include <stdint.h>

#define BB 8
#define TT 2048
#define DD 512

typedef __attribute__((ext_vector_type(8))) __bf16 bf16x8;
typedef __attribute__((ext_vector_type(4))) float f32x4;

__device__ __forceinline__ unsigned short f2bf(float f) {
    unsigned u = __builtin_bit_cast(unsigned, f);
    unsigned r = u + 0x7fffu + ((u >> 16) & 1u);
    return (unsigned short)(r >> 16);
}

// ---------------- gates ----------------
__device__ __forceinline__ float dot512(const float* __restrict__ w, const float* s) {
    const float4* w4 = (const float4*)w;
    const float4* s4 = (const float4*)s;
    float acc = 0.f;
#pragma unroll 8
    for (int i = 0; i < DD / 4; i++) {
        float4 a = w4[i], b = s4[i];
        acc += a.x * b.x + a.y * b.y + a.z * b.z + a.w * b.w;
    }
    return acc;
}

__device__ float gate_one(int tid, const float* saux,
                          const float* __restrict__ W, const float* __restrict__ bias,
                          const float* __restrict__ alpha, const float* __restrict__ g,
                          const float* __restrict__ beta,
                          float* red, float* red2) {
    float h = dot512(W + tid * DD, saux) + bias[tid];
    float a = alpha[0];
    h = (h >= 0.f) ? h : a * h;
    red[tid] = h;
    red2[tid] = h * h;
    __syncthreads();
    for (int s = 256; s > 0; s >>= 1) {
        if (tid < s) { red[tid] += red[tid + s]; red2[tid] += red2[tid + s]; }
        __syncthreads();
    }
    float mu = red[0] * (1.f / DD);
    float var = red2[0] * (1.f / DD) - mu * mu;
    __syncthreads();  // red/red2 reused by next call
    float val = (h - mu) * rsqrtf(var + 1e-5f) * g[tid] + beta[tid];
    return 1.f / (1.f + expf(-val));
}

__global__ __launch_bounds__(512) void gates_kernel(
    const float* __restrict__ aux,
    const float* __restrict__ Wqg, const float* __restrict__ bqg, const float* __restrict__ aq,
    const float* __restrict__ gq, const float* __restrict__ betaq,
    const float* __restrict__ Wkg, const float* __restrict__ bkg, const float* __restrict__ ak,
    const float* __restrict__ gk, const float* __restrict__ betak,
    const float* __restrict__ Wvg, const float* __restrict__ bvg, const float* __restrict__ av,
    const float* __restrict__ gv, const float* __restrict__ betav,
    const float* __restrict__ Wsig, const float* __restrict__ bsig,
    const float* __restrict__ Wtan, const float* __restrict__ btan,
    float* __restrict__ qgate, float* __restrict__ kgate, float* __restrict__ vgate) {
    int b = blockIdx.x, tid = threadIdx.x;
    __shared__ float saux[DD];
    __shared__ float svg[DD];
    __shared__ float red[DD], red2[DD];
    saux[tid] = aux[b * DD + tid];
    __syncthreads();
    float g1 = gate_one(tid, saux, Wqg, bqg, aq, gq, betaq, red, red2);
    qgate[b * DD + tid] = g1;
    float g2 = gate_one(tid, saux, Wkg, bkg, ak, gk, betak, red, red2);
    kgate[b * DD + tid] = g2;
    float g3 = gate_one(tid, saux, Wvg, bvg, av, gv, betav, red, red2);
    svg[tid] = g3;
    __syncthreads();
    float s1 = dot512(Wsig + tid * DD, svg) + bsig[tid];
    float s2 = dot512(Wtan + tid * DD, svg) + btan[tid];
    vgate[b * DD + tid] = (1.f / (1.f + expf(-s1))) * tanhf(s2);
}

// ---------------- elementwise prep ----------------
__global__ __launch_bounds__(256) void prep_kernel(
    const float* __restrict__ query, const float* __restrict__ value,
    const float* __restrict__ kgate,
    unsigned short* __restrict__ queryb, unsigned short* __restrict__ kb) {
    int idx = blockIdx.x * 256 + threadIdx.x;  // one float4 group
    float4 q4 = ((const float4*)query)[idx];
    ushort4 oq;
    oq.x = f2bf(q4.x); oq.y = f2bf(q4.y); oq.z = f2bf(q4.z); oq.w = f2bf(q4.w);
    ((ushort4*)queryb)[idx] = oq;
    float4 v4 = ((const float4*)value)[idx];
    int e = idx * 4;
    int b = e >> 20;            // T*D = 2^20
    int d = e & (DD - 1);
    float4 g4 = *(const float4*)(kgate + b * DD + d);
    ushort4 ok;
    ok.x = f2bf(v4.x * g4.x); ok.y = f2bf(v4.y * g4.y);
    ok.z = f2bf(v4.z * g4.z); ok.w = f2bf(v4.w * g4.w);
    ((ushort4*)kb)[idx] = ok;
}

__global__ __launch_bounds__(256) void wconv_kernel(const float* __restrict__ Wq,
                                                    unsigned short* __restrict__ Wqb) {
    int idx = blockIdx.x * 256 + threadIdx.x;
    float4 w4 = ((const float4*)Wq)[idx];
    ushort4 o;
    o.x = f2bf(w4.x); o.y = f2bf(w4.y); o.z = f2bf(w4.z); o.w = f2bf(w4.w);
    ((ushort4*)Wqb)[idx] = o;
}

// vbT[b][d][t] = bf16(value[b][t][d] * vgate[b][d])
__global__ __launch_bounds__(256) void transpose_v(const float* __restrict__ value,
                                                   const float* __restrict__ vgate,
                                                   unsigned short* __restrict__ vbT) {
    __shared__ float tile[32][33];
    int b = blockIdx.z;
    int t0 = blockIdx.x * 32, d0 = blockIdx.y * 32;
    int tx = threadIdx.x, ty = threadIdx.y;
#pragma unroll
    for (int i = 0; i < 4; i++) {
        int t = t0 + ty + i * 8;
        tile[ty + i * 8][tx] = value[((size_t)b * TT + t) * DD + d0 + tx];
    }
    __syncthreads();
#pragma unroll
    for (int i = 0; i < 4; i++) {
        int d = d0 + ty + i * 8;
        float g = vgate[b * DD + d];
        vbT[((size_t)b * DD + d) * TT + t0 + tx] = f2bf(tile[tx][ty + i * 8] * g);
    }
}

// ---------------- GEMM kernels (128x128 tile, BK=32, 4 waves) ----------------
#define GEMM_CORE(APTR, ALDA, BPTR, BLDA, KSTART, KEND)                                   \
    __shared__ __align__(16) unsigned short As[128 * 32];                                 \
    __shared__ __align__(16) unsigned short Bs[128 * 32];                                 \
    int tid = threadIdx.x;                                                                \
    int lane = tid & 63, wid = tid >> 6;                                                  \
    int wm = (wid >> 1) * 64, wn = (wid & 1) * 64;                                        \
    int lm = lane & 15, quad = lane >> 4;                                                 \
    f32x4 acc[4][4];                                                                      \
    _Pragma("unroll") for (int im = 0; im < 4; im++)                                      \
        _Pragma("unroll") for (int in = 0; in < 4; in++)                                  \
            acc[im][in] = (f32x4){0.f, 0.f, 0.f, 0.f};                                    \
    for (int k0 = (KSTART); k0 < (KEND); k0 += 32) {                                      \
        _Pragma("unroll") for (int i = 0; i < 2; i++) {                                   \
            int idx = tid * 8 + i * 2048;                                                 \
            int r = idx >> 5, c = idx & 31;                                               \
            *(uint4*)&As[idx] = *(const uint4*)&(APTR)[(size_t)r * (ALDA) + k0 + c];      \
            *(uint4*)&Bs[idx] = *(const uint4*)&(BPTR)[(size_t)r * (BLDA) + k0 + c];      \
        }                                                                                 \
        __syncthreads();                                                                  \
        bf16x8 af[4], bf_[4];                                                             \
        _Pragma("unroll") for (int i = 0; i < 4; i++)                                     \
            af[i] = *(const bf16x8*)&As[(wm + i * 16 + lm) * 32 + quad * 8];              \
        _Pragma("unroll") for (int i = 0; i < 4; i++)                                     \
            bf_[i] = *(const bf16x8*)&Bs[(wn + i * 16 + lm) * 32 + quad * 8];             \
        _Pragma("unroll") for (int im = 0; im < 4; im++)                                  \
            _Pragma("unroll") for (int in = 0; in < 4; in++)                              \
                acc[im][in] = __builtin_amdgcn_mfma_f32_16x16x32_bf16(af[im], bf_[in],    \
                                                                     acc[im][in], 0, 0, 0);\
        __syncthreads();                                                                  \
    }

// q = (queryb @ Wqb^T + bq) * qgate  -> bf16 qb
__global__ __launch_bounds__(256) void qgemm_kernel(
    const unsigned short* __restrict__ Amat, const unsigned short* __restrict__ Bmat,
    const float* __restrict__ bq, const float* __restrict__ qgate,
    unsigned short* __restrict__ qb) {
    int m0 = blockIdx.x * 128, n0 = blockIdx.y * 128;
    const unsigned short* Ap = Amat + (size_t)m0 * DD;
    const unsigned short* Bp = Bmat + (size_t)n0 * DD;
    GEMM_CORE(Ap, DD, Bp, DD, 0, DD)
    int b = m0 >> 11;
#pragma unroll
    for (int im = 0; im < 4; im++) {
        int row = m0 + wm + im * 16 + quad * 4;
#pragma unroll
        for (int in = 0; in < 4; in++) {
            int col = n0 + wn + in * 16 + lm;
            float bias = bq[col];
            float g = qgate[b * DD + col];
#pragma unroll
            for (int r = 0; r < 4; r++) {
                float v = (acc[im][in][r] + bias) * g;
                qb[(size_t)(row + r) * DD + col] = f2bf(v);
            }
        }
    }
}

// P = exp(qb @ kb^T / sqrt(D)) with causal mask; rowsum accumulated
__global__ __launch_bounds__(256) void scores_kernel(
    const unsigned short* __restrict__ qb, const unsigned short* __restrict__ kb,
    unsigned short* __restrict__ P, float* __restrict__ rowsum) {
    int nt = blockIdx.x, mt = blockIdx.y, b = blockIdx.z;
    if (nt > mt) return;
    int t0 = mt * 128, s0 = nt * 128;
    const unsigned short* Ap = qb + ((size_t)b * TT + t0) * DD;
    const unsigned short* Bp = kb + ((size_t)b * TT + s0) * DD;
    GEMM_CORE(Ap, DD, Bp, DD, 0, DD)
    const float scale = 0.044194173824159216f;  // 1/sqrt(512)
    unsigned short* Pb = P + (size_t)b * TT * TT;
#pragma unroll
    for (int im = 0; im < 4; im++) {
        int tbase = t0 + wm + im * 16 + quad * 4;
        float rs[4] = {0.f, 0.f, 0.f, 0.f};
#pragma unroll
        for (int in = 0; in < 4; in++) {
            int s = s0 + wn + in * 16 + lm;
#pragma unroll
            for (int r = 0; r < 4; r++) {
                float p = (s <= tbase + r) ? expf(acc[im][in][r] * scale) : 0.f;
                Pb[(size_t)(tbase + r) * TT + s] = f2bf(p);
                rs[r] += p;
            }
        }
#pragma unroll
        for (int r = 0; r < 4; r++) {
            float v = rs[r];
            v += __shfl_xor(v, 1, 64);
            v += __shfl_xor(v, 2, 64);
            v += __shfl_xor(v, 4, 64);
            v += __shfl_xor(v, 8, 64);
            if (lm == 0) atomicAdd(&rowsum[b * TT + tbase + r], v);
        }
    }
}

// out = (P @ V) / rowsum, zero rows t >= L
__global__ __launch_bounds__(256) void out_kernel(
    const unsigned short* __restrict__ P, const unsigned short* __restrict__ vbT,
    const float* __restrict__ rowsum, const int* __restrict__ input_len,
    float* __restrict__ out) {
    int nt = blockIdx.x, mt = blockIdx.y, b = blockIdx.z;
    int t0 = mt * 128, n0 = nt * 128;
    const unsigned short* Ap = P + (size_t)b * TT * TT + (size_t)t0 * TT;
    const unsigned short* Bp = vbT + ((size_t)b * DD + n0) * TT;
    int kend = (mt + 1) * 128;
    GEMM_CORE(Ap, TT, Bp, TT, 0, kend)
    int L = input_len[b];
#pragma unroll
    for (int im = 0; im < 4; im++) {
        int tbase = t0 + wm + im * 16 + quad * 4;
#pragma unroll
        for (int r = 0; r < 4; r++) {
            int t = tbase + r;
            float denom = rowsum[b * TT + t];
            float inv = 1.f / denom;
            bool valid = (t < L);
#pragma unroll
            for (int in = 0; in < 4; in++) {
                int n = n0 + wn + in * 16 + lm;
                float o = valid ? acc[im][in][r] * inv : 0.f;
                out[((size_t)b * TT + t) * DD + n] = o;
            }
        }
    }
}

// ---------------- launch ----------------
extern "C" void kernel_launch(void* const* d_in, const int* in_sizes, int n_in,
                              void* d_out, int out_size, void* d_ws, size_t ws_size,
                              hipStream_t stream) {
    const float* query = (const float*)d_in[0];
    const float* value = (const float*)d_in[1];
    const float* aux   = (const float*)d_in[2];
    const int*   ilen  = (const int*)d_in[3];
    const float* Wq    = (const float*)d_in[4];
    const float* bq    = (const float*)d_in[5];
    const float* Wqg   = (const float*)d_in[6];
    const float* bqg   = (const float*)d_in[7];
    const float* aq    = (const float*)d_in[8];
    const float* gq    = (const float*)d_in[9];
    const float* betaq = (const float*)d_in[10];
    const float* Wkg   = (const float*)d_in[11];
    const float* bkg   = (const float*)d_in[12];
    const float* ak    = (const float*)d_in[13];
    const float* gk    = (const float*)d_in[14];
    const float* betak = (const float*)d_in[15];
    const float* Wvg   = (const float*)d_in[16];
    const float* bvg   = (const float*)d_in[17];
    const float* av    = (const float*)d_in[18];
    const float* gv    = (const float*)d_in[19];
    const float* betav = (const float*)d_in[20];
    const float* Wsig  = (const float*)d_in[21];
    const float* bsig  = (const float*)d_in[22];
    const float* Wtan  = (const float*)d_in[23];
    const float* btan  = (const float*)d_in[24];

    char* ws = (char*)d_ws;
    float* qgate          = (float*)(ws + 0);          // 16 KB
    float* kgate          = (float*)(ws + 16384);      // 16 KB
    float* vgate          = (float*)(ws + 32768);      // 16 KB
    float* rowsum         = (float*)(ws + 49152);      // 64 KB
    unsigned short* Wqb   = (unsigned short*)(ws + 114688);    // 512 KB
    unsigned short* queryb= (unsigned short*)(ws + 638976);    // 16 MB
    unsigned short* qb    = (unsigned short*)(ws + 17416192);  // 16 MB
    unsigned short* kb    = (unsigned short*)(ws + 34193408);  // 16 MB
    unsigned short* vbT   = (unsigned short*)(ws + 50970624);  // 16 MB
    unsigned short* P     = (unsigned short*)(ws + 67747840);  // 64 MB  -> total ~128.6 MB

    hipMemsetAsync(rowsum, 0, BB * TT * sizeof(float), stream);

    gates_kernel<<<BB, 512, 0, stream>>>(aux, Wqg, bqg, aq, gq, betaq,
                                         Wkg, bkg, ak, gk, betak,
                                         Wvg, bvg, av, gv, betav,
                                         Wsig, bsig, Wtan, btan,
                                         qgate, kgate, vgate);
    prep_kernel<<<(BB * TT * DD / 4) / 256, 256, 0, stream>>>(query, value, kgate, queryb, kb);
    wconv_kernel<<<(DD * DD / 4) / 256, 256, 0, stream>>>(Wq, Wqb);
    transpose_v<<<dim3(TT / 32, DD / 32, BB), dim3(32, 8), 0, stream>>>(value, vgate, vbT);
    qgemm_kernel<<<dim3((BB * TT) / 128, DD / 128), 256, 0, stream>>>(queryb, Wqb, bq, qgate, qb);
    scores_kernel<<<dim3(TT / 128, TT / 128, BB), 256, 0, stream>>>(qb, kb, P, rowsum);
    out_kernel<<<dim3(DD / 128, TT / 128, BB), 256, 0, stream>>>(P, vbT, rowsum, ilen, (float*)d_out);
}

// Round 2
// 330.565 us; speedup vs baseline: 1.4176x; 1.4176x over previous
//
#include <hip/hip_runtime.h>
#include <hip/hip_bf16.h>
#include <stdint.h>

#define BB 8
#define TT 2048
#define DD 512

typedef __attribute__((ext_vector_type(8))) __bf16 bf16x8;
typedef __attribute__((ext_vector_type(4))) float f32x4;

__device__ __forceinline__ unsigned short f2bf(float f) {
    unsigned u = __builtin_bit_cast(unsigned, f);
    unsigned r = u + 0x7fffu + ((u >> 16) & 1u);
    return (unsigned short)(r >> 16);
}

// ---------------- gates (wave-per-row matvec, all batches at once) ----------------
// h[g][b][r] = leaky(W_g[r] . aux[b] + bias_g[r])
__global__ __launch_bounds__(256) void gates_mv1(
    const float* __restrict__ aux,
    const float* __restrict__ Wqg, const float* __restrict__ bqg, const float* __restrict__ aq,
    const float* __restrict__ Wkg, const float* __restrict__ bkg, const float* __restrict__ ak,
    const float* __restrict__ Wvg, const float* __restrict__ bvg, const float* __restrict__ av,
    float* __restrict__ h) {
    __shared__ float saux[BB * DD];
    int tid = threadIdx.x;
#pragma unroll
    for (int i = 0; i < 4; i++) {
        int idx = tid + i * 256;
        ((float4*)saux)[idx] = ((const float4*)aux)[idx];
    }
    __syncthreads();
    int wave = (blockIdx.x * 256 + tid) >> 6;  // 0..1535
    int lane = tid & 63;
    int g = wave >> 9, r = wave & 511;
    const float* W    = (g == 0) ? Wqg : (g == 1) ? Wkg : Wvg;
    const float* bias = (g == 0) ? bqg : (g == 1) ? bkg : bvg;
    const float* alpha = (g == 0) ? aq : (g == 1) ? ak : av;
    const float4* Wrow = (const float4*)(W + (size_t)r * DD);
    float acc[BB];
#pragma unroll
    for (int b = 0; b < BB; b++) acc[b] = 0.f;
#pragma unroll
    for (int c = 0; c < 2; c++) {
        float4 w4 = Wrow[lane + c * 64];
#pragma unroll
        for (int b = 0; b < BB; b++) {
            float4 a4 = ((const float4*)(saux + b * DD))[lane + c * 64];
            acc[b] += w4.x * a4.x + w4.y * a4.y + w4.z * a4.z + w4.w * a4.w;
        }
    }
#pragma unroll
    for (int b = 0; b < BB; b++) {
#pragma unroll
        for (int s = 1; s < 64; s <<= 1) acc[b] += __shfl_xor(acc[b], s, 64);
    }
    if (lane == 0) {
        float bi = bias[r], a = alpha[0];
#pragma unroll
        for (int b = 0; b < BB; b++) {
            float v = acc[b] + bi;
            v = (v >= 0.f) ? v : a * v;
            h[(g * BB + b) * DD + r] = v;
        }
    }
}

// layernorm + sigmoid per (gate,batch); writes qgate/kgate/vg
__global__ __launch_bounds__(512) void gates_norm(
    const float* __restrict__ h,
    const float* __restrict__ gq, const float* __restrict__ betaq,
    const float* __restrict__ gk, const float* __restrict__ betak,
    const float* __restrict__ gv, const float* __restrict__ betav,
    float* __restrict__ qgate, float* __restrict__ kgate, float* __restrict__ vg) {
    int g = blockIdx.x >> 3, b = blockIdx.x & 7, tid = threadIdx.x;
    __shared__ float red[DD], red2[DD];
    float hv = h[(g * BB + b) * DD + tid];
    red[tid] = hv; red2[tid] = hv * hv;
    __syncthreads();
    for (int s = 256; s > 0; s >>= 1) {
        if (tid < s) { red[tid] += red[tid + s]; red2[tid] += red2[tid + s]; }
        __syncthreads();
    }
    float mu = red[0] * (1.f / DD);
    float var = red2[0] * (1.f / DD) - mu * mu;
    const float* gg = (g == 0) ? gq : (g == 1) ? gk : gv;
    const float* be = (g == 0) ? betaq : (g == 1) ? betak : betav;
    float val = (hv - mu) * rsqrtf(var + 1e-5f) * gg[tid] + be[tid];
    float sg = 1.f / (1.f + expf(-val));
    float* outp = (g == 0) ? qgate : (g == 1) ? kgate : vg;
    outp[b * DD + tid] = sg;
}

// vgate[b][r] = sigmoid(Wsig[r].vg[b]+bsig[r]) * tanh(Wtan[r].vg[b]+btan[r])
__global__ __launch_bounds__(256) void gates_mv2(
    const float* __restrict__ vg,
    const float* __restrict__ Wsig, const float* __restrict__ bsig,
    const float* __restrict__ Wtan, const float* __restrict__ btan,
    float* __restrict__ vgate) {
    __shared__ float svg[BB * DD];
    int tid = threadIdx.x;
#pragma unroll
    for (int i = 0; i < 4; i++) {
        int idx = tid + i * 256;
        ((float4*)svg)[idx] = ((const float4*)vg)[idx];
    }
    __syncthreads();
    int r = (blockIdx.x * 256 + tid) >> 6;  // 0..511
    int lane = tid & 63;
    const float4* Ws = (const float4*)(Wsig + (size_t)r * DD);
    const float4* Wt = (const float4*)(Wtan + (size_t)r * DD);
    float as_[BB], at_[BB];
#pragma unroll
    for (int b = 0; b < BB; b++) { as_[b] = 0.f; at_[b] = 0.f; }
#pragma unroll
    for (int c = 0; c < 2; c++) {
        float4 w1 = Ws[lane + c * 64];
        float4 w2 = Wt[lane + c * 64];
#pragma unroll
        for (int b = 0; b < BB; b++) {
            float4 a4 = ((const float4*)(svg + b * DD))[lane + c * 64];
            as_[b] += w1.x * a4.x + w1.y * a4.y + w1.z * a4.z + w1.w * a4.w;
            at_[b] += w2.x * a4.x + w2.y * a4.y + w2.z * a4.z + w2.w * a4.w;
        }
    }
#pragma unroll
    for (int b = 0; b < BB; b++) {
#pragma unroll
        for (int s = 1; s < 64; s <<= 1) {
            as_[b] += __shfl_xor(as_[b], s, 64);
            at_[b] += __shfl_xor(at_[b], s, 64);
        }
    }
    if (lane == 0) {
        float b1 = bsig[r], b2 = btan[r];
#pragma unroll
        for (int b = 0; b < BB; b++) {
            float s1 = 1.f / (1.f + expf(-(as_[b] + b1)));
            float s2 = tanhf(at_[b] + b2);
            vgate[b * DD + r] = s1 * s2;
        }
    }
}

// ---------------- elementwise prep ----------------
__global__ __launch_bounds__(256) void prep_kernel(
    const float* __restrict__ query, const float* __restrict__ value,
    const float* __restrict__ kgate,
    unsigned short* __restrict__ queryb, unsigned short* __restrict__ kb) {
    int idx = blockIdx.x * 256 + threadIdx.x;  // one float4 group
    float4 q4 = ((const float4*)query)[idx];
    ushort4 oq;
    oq.x = f2bf(q4.x); oq.y = f2bf(q4.y); oq.z = f2bf(q4.z); oq.w = f2bf(q4.w);
    ((ushort4*)queryb)[idx] = oq;
    float4 v4 = ((const float4*)value)[idx];
    int e = idx * 4;
    int b = e >> 20;            // T*D = 2^20
    int d = e & (DD - 1);
    float4 g4 = *(const float4*)(kgate + b * DD + d);
    ushort4 ok;
    ok.x = f2bf(v4.x * g4.x); ok.y = f2bf(v4.y * g4.y);
    ok.z = f2bf(v4.z * g4.z); ok.w = f2bf(v4.w * g4.w);
    ((ushort4*)kb)[idx] = ok;
}

__global__ __launch_bounds__(256) void wconv_kernel(const float* __restrict__ Wq,
                                                    unsigned short* __restrict__ Wqb) {
    int idx = blockIdx.x * 256 + threadIdx.x;
    float4 w4 = ((const float4*)Wq)[idx];
    ushort4 o;
    o.x = f2bf(w4.x); o.y = f2bf(w4.y); o.z = f2bf(w4.z); o.w = f2bf(w4.w);
    ((ushort4*)Wqb)[idx] = o;
}

// vbT[b][d][t] = bf16(value[b][t][d] * vgate[b][d])
__global__ __launch_bounds__(256) void transpose_v(const float* __restrict__ value,
                                                   const float* __restrict__ vgate,
                                                   unsigned short* __restrict__ vbT) {
    __shared__ float tile[32][33];
    int b = blockIdx.z;
    int t0 = blockIdx.x * 32, d0 = blockIdx.y * 32;
    int tx = threadIdx.x, ty = threadIdx.y;
#pragma unroll
    for (int i = 0; i < 4; i++) {
        int t = t0 + ty + i * 8;
        tile[ty + i * 8][tx] = value[((size_t)b * TT + t) * DD + d0 + tx];
    }
    __syncthreads();
#pragma unroll
    for (int i = 0; i < 4; i++) {
        int d = d0 + ty + i * 8;
        float g = vgate[b * DD + d];
        vbT[((size_t)b * DD + d) * TT + t0 + tx] = f2bf(tile[tx][ty + i * 8] * g);
    }
}

// ---------------- GEMM kernels (128x128 tile, BK=32, 4 waves) ----------------
#define GEMM_CORE(APTR, ALDA, BPTR, BLDA, KSTART, KEND)                                   \
    __shared__ __align__(16) unsigned short As[128 * 32];                                 \
    __shared__ __align__(16) unsigned short Bs[128 * 32];                                 \
    int tid = threadIdx.x;                                                                \
    int lane = tid & 63, wid = tid >> 6;                                                  \
    int wm = (wid >> 1) * 64, wn = (wid & 1) * 64;                                        \
    int lm = lane & 15, quad = lane >> 4;                                                 \
    f32x4 acc[4][4];                                                                      \
    _Pragma("unroll") for (int im = 0; im < 4; im++)                                      \
        _Pragma("unroll") for (int in = 0; in < 4; in++)                                  \
            acc[im][in] = (f32x4){0.f, 0.f, 0.f, 0.f};                                    \
    for (int k0 = (KSTART); k0 < (KEND); k0 += 32) {                                      \
        _Pragma("unroll") for (int i = 0; i < 2; i++) {                                   \
            int idx = tid * 8 + i * 2048;                                                 \
            int r = idx >> 5, c = idx & 31;                                               \
            *(uint4*)&As[idx] = *(const uint4*)&(APTR)[(size_t)r * (ALDA) + k0 + c];      \
            *(uint4*)&Bs[idx] = *(const uint4*)&(BPTR)[(size_t)r * (BLDA) + k0 + c];      \
        }                                                                                 \
        __syncthreads();                                                                  \
        bf16x8 af[4], bf_[4];                                                             \
        _Pragma("unroll") for (int i = 0; i < 4; i++)                                     \
            af[i] = *(const bf16x8*)&As[(wm + i * 16 + lm) * 32 + quad * 8];              \
        _Pragma("unroll") for (int i = 0; i < 4; i++)                                     \
            bf_[i] = *(const bf16x8*)&Bs[(wn + i * 16 + lm) * 32 + quad * 8];             \
        _Pragma("unroll") for (int im = 0; im < 4; im++)                                  \
            _Pragma("unroll") for (int in = 0; in < 4; in++)                              \
                acc[im][in] = __builtin_amdgcn_mfma_f32_16x16x32_bf16(af[im], bf_[in],    \
                                                                     acc[im][in], 0, 0, 0);\
        __syncthreads();                                                                  \
    }

// q = (queryb @ Wqb^T + bq) * qgate  -> bf16 qb
__global__ __launch_bounds__(256) void qgemm_kernel(
    const unsigned short* __restrict__ Amat, const unsigned short* __restrict__ Bmat,
    const float* __restrict__ bq, const float* __restrict__ qgate,
    unsigned short* __restrict__ qb) {
    int m0 = blockIdx.x * 128, n0 = blockIdx.y * 128;
    const unsigned short* Ap = Amat + (size_t)m0 * DD;
    const unsigned short* Bp = Bmat + (size_t)n0 * DD;
    GEMM_CORE(Ap, DD, Bp, DD, 0, DD)
    int b = m0 >> 11;
#pragma unroll
    for (int im = 0; im < 4; im++) {
        int row = m0 + wm + im * 16 + quad * 4;
#pragma unroll
        for (int in = 0; in < 4; in++) {
            int col = n0 + wn + in * 16 + lm;
            float bias = bq[col];
            float g = qgate[b * DD + col];
#pragma unroll
            for (int r = 0; r < 4; r++) {
                float v = (acc[im][in][r] + bias) * g;
                qb[(size_t)(row + r) * DD + col] = f2bf(v);
            }
        }
    }
}

// P = exp(qb @ kb^T / sqrt(D)) with causal mask; rowsum accumulated
__global__ __launch_bounds__(256) void scores_kernel(
    const unsigned short* __restrict__ qb, const unsigned short* __restrict__ kb,
    unsigned short* __restrict__ P, float* __restrict__ rowsum) {
    int nt = blockIdx.x, mt = blockIdx.y, b = blockIdx.z;
    if (nt > mt) return;
    int t0 = mt * 128, s0 = nt * 128;
    const unsigned short* Ap = qb + ((size_t)b * TT + t0) * DD;
    const unsigned short* Bp = kb + ((size_t)b * TT + s0) * DD;
    GEMM_CORE(Ap, DD, Bp, DD, 0, DD)
    const float scale = 0.044194173824159216f;  // 1/sqrt(512)
    unsigned short* Pb = P + (size_t)b * TT * TT;
#pragma unroll
    for (int im = 0; im < 4; im++) {
        int tbase = t0 + wm + im * 16 + quad * 4;
        float rs[4] = {0.f, 0.f, 0.f, 0.f};
#pragma unroll
        for (int in = 0; in < 4; in++) {
            int s = s0 + wn + in * 16 + lm;
#pragma unroll
            for (int r = 0; r < 4; r++) {
                float p = (s <= tbase + r) ? expf(acc[im][in][r] * scale) : 0.f;
                Pb[(size_t)(tbase + r) * TT + s] = f2bf(p);
                rs[r] += p;
            }
        }
#pragma unroll
        for (int r = 0; r < 4; r++) {
            float v = rs[r];
            v += __shfl_xor(v, 1, 64);
            v += __shfl_xor(v, 2, 64);
            v += __shfl_xor(v, 4, 64);
            v += __shfl_xor(v, 8, 64);
            if (lm == 0) atomicAdd(&rowsum[b * TT + tbase + r], v);
        }
    }
}

// out = (P @ V) / rowsum, zero rows t >= L
__global__ __launch_bounds__(256) void out_kernel(
    const unsigned short* __restrict__ P, const unsigned short* __restrict__ vbT,
    const float* __restrict__ rowsum, const int* __restrict__ input_len,
    float* __restrict__ out) {
    int nt = blockIdx.x, mt = blockIdx.y, b = blockIdx.z;
    int t0 = mt * 128, n0 = nt * 128;
    const unsigned short* Ap = P + (size_t)b * TT * TT + (size_t)t0 * TT;
    const unsigned short* Bp = vbT + ((size_t)b * DD + n0) * TT;
    int kend = (mt + 1) * 128;
    GEMM_CORE(Ap, TT, Bp, TT, 0, kend)
    int L = input_len[b];
#pragma unroll
    for (int im = 0; im < 4; im++) {
        int tbase = t0 + wm + im * 16 + quad * 4;
#pragma unroll
        for (int r = 0; r < 4; r++) {
            int t = tbase + r;
            float denom = rowsum[b * TT + t];
            float inv = 1.f / denom;
            bool valid = (t < L);
#pragma unroll
            for (int in = 0; in < 4; in++) {
                int n = n0 + wn + in * 16 + lm;
                float o = valid ? acc[im][in][r] * inv : 0.f;
                out[((size_t)b * TT + t) * DD + n] = o;
            }
        }
    }
}

// ---------------- launch ----------------
extern "C" void kernel_launch(void* const* d_in, const int* in_sizes, int n_in,
                              void* d_out, int out_size, void* d_ws, size_t ws_size,
                              hipStream_t stream) {
    const float* query = (const float*)d_in[0];
    const float* value = (const float*)d_in[1];
    const float* aux   = (const float*)d_in[2];
    const int*   ilen  = (const int*)d_in[3];
    const float* Wq    = (const float*)d_in[4];
    const float* bq    = (const float*)d_in[5];
    const float* Wqg   = (const float*)d_in[6];
    const float* bqg   = (const float*)d_in[7];
    const float* aq    = (const float*)d_in[8];
    const float* gq    = (const float*)d_in[9];
    const float* betaq = (const float*)d_in[10];
    const float* Wkg   = (const float*)d_in[11];
    const float* bkg   = (const float*)d_in[12];
    const float* ak    = (const float*)d_in[13];
    const float* gk    = (const float*)d_in[14];
    const float* betak = (const float*)d_in[15];
    const float* Wvg   = (const float*)d_in[16];
    const float* bvg   = (const float*)d_in[17];
    const float* av    = (const float*)d_in[18];
    const float* gv    = (const float*)d_in[19];
    const float* betav = (const float*)d_in[20];
    const float* Wsig  = (const float*)d_in[21];
    const float* bsig  = (const float*)d_in[22];
    const float* Wtan  = (const float*)d_in[23];
    const float* btan  = (const float*)d_in[24];

    char* ws = (char*)d_ws;
    float* qgate          = (float*)(ws + 0);          // 16 KB
    float* kgate          = (float*)(ws + 16384);      // 16 KB
    float* vgate          = (float*)(ws + 32768);      // 16 KB
    float* rowsum         = (float*)(ws + 49152);      // 64 KB
    unsigned short* Wqb   = (unsigned short*)(ws + 114688);    // 512 KB
    unsigned short* queryb= (unsigned short*)(ws + 638976);    // 16 MB
    unsigned short* qb    = (unsigned short*)(ws + 17416192);  // 16 MB
    unsigned short* kb    = (unsigned short*)(ws + 34193408);  // 16 MB
    unsigned short* vbT   = (unsigned short*)(ws + 50970624);  // 16 MB
    unsigned short* P     = (unsigned short*)(ws + 67747840);  // 64 MB  -> total ~128.6 MB
    // gate scratch overlays the P region (P is written only later, in scores_kernel)
    float* hbuf           = (float*)(ws + 67747840);           // 48 KB  (3*8*512 f32)
    float* vg             = (float*)(ws + 67747840 + 49152);   // 16 KB

    hipMemsetAsync(rowsum, 0, BB * TT * sizeof(float), stream);

    gates_mv1<<<384, 256, 0, stream>>>(aux, Wqg, bqg, aq, Wkg, bkg, ak, Wvg, bvg, av, hbuf);
    gates_norm<<<24, 512, 0, stream>>>(hbuf, gq, betaq, gk, betak, gv, betav,
                                       qgate, kgate, vg);
    gates_mv2<<<128, 256, 0, stream>>>(vg, Wsig, bsig, Wtan, btan, vgate);

    prep_kernel<<<(BB * TT * DD / 4) / 256, 256, 0, stream>>>(query, value, kgate, queryb, kb);
    wconv_kernel<<<(DD * DD / 4) / 256, 256, 0, stream>>>(Wq, Wqb);
    transpose_v<<<dim3(TT / 32, DD / 32, BB), dim3(32, 8), 0, stream>>>(value, vgate, vbT);
    qgemm_kernel<<<dim3((BB * TT) / 128, DD / 128), 256, 0, stream>>>(queryb, Wqb, bq, qgate, qb);
    scores_kernel<<<dim3(TT / 128, TT / 128, BB), 256, 0, stream>>>(qb, kb, P, rowsum);
    out_kernel<<<dim3(DD / 128, TT / 128, BB), 256, 0, stream>>>(P, vbT, rowsum, ilen, (float*)d_out);
}

// Round 3
// 294.452 us; speedup vs baseline: 1.5915x; 1.1226x over previous
//
#include <hip/hip_runtime.h>
#include <hip/hip_bf16.h>
#include <stdint.h>

#define BB 8
#define TT 2048
#define DD 512

typedef __attribute__((ext_vector_type(8))) __bf16 bf16x8;
typedef __attribute__((ext_vector_type(4))) float f32x4;

__device__ __forceinline__ unsigned short f2bf(float f) {
    unsigned u = __builtin_bit_cast(unsigned, f);
    unsigned r = u + 0x7fffu + ((u >> 16) & 1u);
    return (unsigned short)(r >> 16);
}

// async global->LDS DMA, 16B per lane. LDS dest must be wave-uniform base + lane*16.
__device__ __forceinline__ void gload_lds16(const unsigned short* g, unsigned short* l) {
    __builtin_amdgcn_global_load_lds(
        (const __attribute__((address_space(1))) void*)g,
        (__attribute__((address_space(3))) void*)l, 16, 0, 0);
}

// ---------------- gates (wave-per-row matvec, all batches at once) ----------------
__global__ __launch_bounds__(256) void gates_mv1(
    const float* __restrict__ aux,
    const float* __restrict__ Wqg, const float* __restrict__ bqg, const float* __restrict__ aq,
    const float* __restrict__ Wkg, const float* __restrict__ bkg, const float* __restrict__ ak,
    const float* __restrict__ Wvg, const float* __restrict__ bvg, const float* __restrict__ av,
    float* __restrict__ h) {
    __shared__ float saux[BB * DD];
    int tid = threadIdx.x;
#pragma unroll
    for (int i = 0; i < 4; i++) {
        int idx = tid + i * 256;
        ((float4*)saux)[idx] = ((const float4*)aux)[idx];
    }
    __syncthreads();
    int wave = (blockIdx.x * 256 + tid) >> 6;  // 0..1535
    int lane = tid & 63;
    int g = wave >> 9, r = wave & 511;
    const float* W    = (g == 0) ? Wqg : (g == 1) ? Wkg : Wvg;
    const float* bias = (g == 0) ? bqg : (g == 1) ? bkg : bvg;
    const float* alpha = (g == 0) ? aq : (g == 1) ? ak : av;
    const float4* Wrow = (const float4*)(W + (size_t)r * DD);
    float acc[BB];
#pragma unroll
    for (int b = 0; b < BB; b++) acc[b] = 0.f;
#pragma unroll
    for (int c = 0; c < 2; c++) {
        float4 w4 = Wrow[lane + c * 64];
#pragma unroll
        for (int b = 0; b < BB; b++) {
            float4 a4 = ((const float4*)(saux + b * DD))[lane + c * 64];
            acc[b] += w4.x * a4.x + w4.y * a4.y + w4.z * a4.z + w4.w * a4.w;
        }
    }
#pragma unroll
    for (int b = 0; b < BB; b++) {
#pragma unroll
        for (int s = 1; s < 64; s <<= 1) acc[b] += __shfl_xor(acc[b], s, 64);
    }
    if (lane == 0) {
        float bi = bias[r], a = alpha[0];
#pragma unroll
        for (int b = 0; b < BB; b++) {
            float v = acc[b] + bi;
            v = (v >= 0.f) ? v : a * v;
            h[(g * BB + b) * DD + r] = v;
        }
    }
}

__global__ __launch_bounds__(512) void gates_norm(
    const float* __restrict__ h,
    const float* __restrict__ gq, const float* __restrict__ betaq,
    const float* __restrict__ gk, const float* __restrict__ betak,
    const float* __restrict__ gv, const float* __restrict__ betav,
    float* __restrict__ qgate, float* __restrict__ kgate, float* __restrict__ vg) {
    int g = blockIdx.x >> 3, b = blockIdx.x & 7, tid = threadIdx.x;
    __shared__ float red[DD], red2[DD];
    float hv = h[(g * BB + b) * DD + tid];
    red[tid] = hv; red2[tid] = hv * hv;
    __syncthreads();
    for (int s = 256; s > 0; s >>= 1) {
        if (tid < s) { red[tid] += red[tid + s]; red2[tid] += red2[tid + s]; }
        __syncthreads();
    }
    float mu = red[0] * (1.f / DD);
    float var = red2[0] * (1.f / DD) - mu * mu;
    const float* gg = (g == 0) ? gq : (g == 1) ? gk : gv;
    const float* be = (g == 0) ? betaq : (g == 1) ? betak : betav;
    float val = (hv - mu) * rsqrtf(var + 1e-5f) * gg[tid] + be[tid];
    float sg = 1.f / (1.f + expf(-val));
    float* outp = (g == 0) ? qgate : (g == 1) ? kgate : vg;
    outp[b * DD + tid] = sg;
}

__global__ __launch_bounds__(256) void gates_mv2(
    const float* __restrict__ vg,
    const float* __restrict__ Wsig, const float* __restrict__ bsig,
    const float* __restrict__ Wtan, const float* __restrict__ btan,
    float* __restrict__ vgate) {
    __shared__ float svg[BB * DD];
    int tid = threadIdx.x;
#pragma unroll
    for (int i = 0; i < 4; i++) {
        int idx = tid + i * 256;
        ((float4*)svg)[idx] = ((const float4*)vg)[idx];
    }
    __syncthreads();
    int r = (blockIdx.x * 256 + tid) >> 6;  // 0..511
    int lane = tid & 63;
    const float4* Ws = (const float4*)(Wsig + (size_t)r * DD);
    const float4* Wt = (const float4*)(Wtan + (size_t)r * DD);
    float as_[BB], at_[BB];
#pragma unroll
    for (int b = 0; b < BB; b++) { as_[b] = 0.f; at_[b] = 0.f; }
#pragma unroll
    for (int c = 0; c < 2; c++) {
        float4 w1 = Ws[lane + c * 64];
        float4 w2 = Wt[lane + c * 64];
#pragma unroll
        for (int b = 0; b < BB; b++) {
            float4 a4 = ((const float4*)(svg + b * DD))[lane + c * 64];
            as_[b] += w1.x * a4.x + w1.y * a4.y + w1.z * a4.z + w1.w * a4.w;
            at_[b] += w2.x * a4.x + w2.y * a4.y + w2.z * a4.z + w2.w * a4.w;
        }
    }
#pragma unroll
    for (int b = 0; b < BB; b++) {
#pragma unroll
        for (int s = 1; s < 64; s <<= 1) {
            as_[b] += __shfl_xor(as_[b], s, 64);
            at_[b] += __shfl_xor(at_[b], s, 64);
        }
    }
    if (lane == 0) {
        float b1 = bsig[r], b2 = btan[r];
#pragma unroll
        for (int b = 0; b < BB; b++) {
            float s1 = 1.f / (1.f + expf(-(as_[b] + b1)));
            float s2 = tanhf(at_[b] + b2);
            vgate[b * DD + r] = s1 * s2;
        }
    }
}

// ---------------- elementwise prep ----------------
// query -> bf16 only (value handled in vk_kernel)
__global__ __launch_bounds__(256) void prep_kernel(
    const float* __restrict__ query, unsigned short* __restrict__ queryb) {
    int idx = blockIdx.x * 256 + threadIdx.x;
    float4 q4 = ((const float4*)query)[idx];
    ushort4 oq;
    oq.x = f2bf(q4.x); oq.y = f2bf(q4.y); oq.z = f2bf(q4.z); oq.w = f2bf(q4.w);
    ((ushort4*)queryb)[idx] = oq;
}

__global__ __launch_bounds__(256) void wconv_kernel(const float* __restrict__ Wq,
                                                    unsigned short* __restrict__ Wqb) {
    int idx = blockIdx.x * 256 + threadIdx.x;
    float4 w4 = ((const float4*)Wq)[idx];
    ushort4 o;
    o.x = f2bf(w4.x); o.y = f2bf(w4.y); o.z = f2bf(w4.z); o.w = f2bf(w4.w);
    ((ushort4*)Wqb)[idx] = o;
}

// reads value once: kb[b][t][d] = bf16(v*kgate), vbT[b][d][t] = bf16(v*vgate)
__global__ __launch_bounds__(256) void vk_kernel(const float* __restrict__ value,
                                                 const float* __restrict__ kgate,
                                                 const float* __restrict__ vgate,
                                                 unsigned short* __restrict__ kb,
                                                 unsigned short* __restrict__ vbT) {
    __shared__ float tile[32][33];
    int b = blockIdx.z;
    int t0 = blockIdx.x * 32, d0 = blockIdx.y * 32;
    int tx = threadIdx.x, ty = threadIdx.y;
    float kg = kgate[b * DD + d0 + tx];
#pragma unroll
    for (int i = 0; i < 4; i++) {
        int t = t0 + ty + i * 8;
        float v = value[((size_t)b * TT + t) * DD + d0 + tx];
        tile[ty + i * 8][tx] = v;
        kb[((size_t)b * TT + t) * DD + d0 + tx] = f2bf(v * kg);
    }
    __syncthreads();
#pragma unroll
    for (int i = 0; i < 4; i++) {
        int d = d0 + ty + i * 8;
        float g = vgate[b * DD + d];
        vbT[((size_t)b * DD + d) * TT + t0 + tx] = f2bf(tile[tx][ty + i * 8] * g);
    }
}

// ---------------- GEMM core (128x128 tile, BK=32, 4 waves) ----------------
// global->LDS via async DMA (16B/lane); XOR chunk swizzle (c ^ ((r>>1)&3)) makes
// the ds_read_b128 fragment reads exactly 2-way bank-aliased (free, m136).
#define GEMM_CORE(APTR, ALDA, BPTR, BLDA, KSTART, KEND)                                   \
    __shared__ __align__(16) unsigned short As[128 * 32];                                 \
    __shared__ __align__(16) unsigned short Bs[128 * 32];                                 \
    int tid = threadIdx.x;                                                                \
    int lane = tid & 63, wid = tid >> 6;                                                  \
    int wm = (wid >> 1) * 64, wn = (wid & 1) * 64;                                        \
    int lm = lane & 15, quad = lane >> 4;                                                 \
    f32x4 acc[4][4];                                                                      \
    _Pragma("unroll") for (int im = 0; im < 4; im++)                                      \
        _Pragma("unroll") for (int in = 0; in < 4; in++)                                  \
            acc[im][in] = (f32x4){0.f, 0.f, 0.f, 0.f};                                    \
    for (int k0 = (KSTART); k0 < (KEND); k0 += 32) {                                      \
        _Pragma("unroll") for (int i = 0; i < 2; i++) {                                   \
            int idx = tid * 8 + i * 2048;                                                 \
            int r = idx >> 5;                                                             \
            int cg = ((idx >> 3) & 3) ^ ((r >> 1) & 3);                                   \
            gload_lds16(&(APTR)[(size_t)r * (ALDA) + k0 + cg * 8], &As[idx]);             \
            gload_lds16(&(BPTR)[(size_t)r * (BLDA) + k0 + cg * 8], &Bs[idx]);             \
        }                                                                                 \
        __syncthreads();                                                                  \
        bf16x8 af[4], bf_[4];                                                             \
        _Pragma("unroll") for (int i = 0; i < 4; i++) {                                   \
            int row = wm + i * 16 + lm;                                                   \
            af[i] = *(const bf16x8*)&As[row * 32 + (quad ^ ((row >> 1) & 3)) * 8];        \
        }                                                                                 \
        _Pragma("unroll") for (int i = 0; i < 4; i++) {                                   \
            int row = wn + i * 16 + lm;                                                   \
            bf_[i] = *(const bf16x8*)&Bs[row * 32 + (quad ^ ((row >> 1) & 3)) * 8];       \
        }                                                                                 \
        _Pragma("unroll") for (int im = 0; im < 4; im++)                                  \
            _Pragma("unroll") for (int in = 0; in < 4; in++)                              \
                acc[im][in] = __builtin_amdgcn_mfma_f32_16x16x32_bf16(af[im], bf_[in],    \
                                                                     acc[im][in], 0, 0, 0);\
        __syncthreads();                                                                  \
    }

// q = (queryb @ Wqb^T + bq) * qgate  -> bf16 qb
__global__ __launch_bounds__(256) void qgemm_kernel(
    const unsigned short* __restrict__ Amat, const unsigned short* __restrict__ Bmat,
    const float* __restrict__ bq, const float* __restrict__ qgate,
    unsigned short* __restrict__ qb) {
    int m0 = blockIdx.x * 128, n0 = blockIdx.y * 128;
    const unsigned short* Ap = Amat + (size_t)m0 * DD;
    const unsigned short* Bp = Bmat + (size_t)n0 * DD;
    GEMM_CORE(Ap, DD, Bp, DD, 0, DD)
    int b = m0 >> 11;
#pragma unroll
    for (int im = 0; im < 4; im++) {
        int row = m0 + wm + im * 16 + quad * 4;
#pragma unroll
        for (int in = 0; in < 4; in++) {
            int col = n0 + wn + in * 16 + lm;
            float bias = bq[col];
            float g = qgate[b * DD + col];
#pragma unroll
            for (int r = 0; r < 4; r++) {
                float v = (acc[im][in][r] + bias) * g;
                qb[(size_t)(row + r) * DD + col] = f2bf(v);
            }
        }
    }
}

// P = exp(qb @ kb^T / sqrt(D)) with causal mask; rowsum accumulated.
// grid.x enumerates only lower-triangle tile pairs.
__global__ __launch_bounds__(256) void scores_kernel(
    const unsigned short* __restrict__ qb, const unsigned short* __restrict__ kb,
    unsigned short* __restrict__ P, float* __restrict__ rowsum) {
    int b = blockIdx.z;
    int idx = blockIdx.x;
    int mt = (int)((sqrtf(8.f * idx + 1.f) - 1.f) * 0.5f);
    while ((mt + 1) * (mt + 2) / 2 <= idx) mt++;
    while (mt * (mt + 1) / 2 > idx) mt--;
    int nt = idx - mt * (mt + 1) / 2;
    int t0 = mt * 128, s0 = nt * 128;
    const unsigned short* Ap = qb + ((size_t)b * TT + t0) * DD;
    const unsigned short* Bp = kb + ((size_t)b * TT + s0) * DD;
    GEMM_CORE(Ap, DD, Bp, DD, 0, DD)
    const float scale = 0.044194173824159216f;  // 1/sqrt(512)
    unsigned short* Pb = P + (size_t)b * TT * TT;
#pragma unroll
    for (int im = 0; im < 4; im++) {
        int tbase = t0 + wm + im * 16 + quad * 4;
        float rs[4] = {0.f, 0.f, 0.f, 0.f};
#pragma unroll
        for (int in = 0; in < 4; in++) {
            int s = s0 + wn + in * 16 + lm;
#pragma unroll
            for (int r = 0; r < 4; r++) {
                float p = (s <= tbase + r) ? expf(acc[im][in][r] * scale) : 0.f;
                Pb[(size_t)(tbase + r) * TT + s] = f2bf(p);
                rs[r] += p;
            }
        }
#pragma unroll
        for (int r = 0; r < 4; r++) {
            float v = rs[r];
            v += __shfl_xor(v, 1, 64);
            v += __shfl_xor(v, 2, 64);
            v += __shfl_xor(v, 4, 64);
            v += __shfl_xor(v, 8, 64);
            if (lm == 0) atomicAdd(&rowsum[b * TT + tbase + r], v);
        }
    }
}

// out = (P @ V) / rowsum, zero rows t >= L
__global__ __launch_bounds__(256) void out_kernel(
    const unsigned short* __restrict__ P, const unsigned short* __restrict__ vbT,
    const float* __restrict__ rowsum, const int* __restrict__ input_len,
    float* __restrict__ out) {
    int nt = blockIdx.x, mt = blockIdx.y, b = blockIdx.z;
    int t0 = mt * 128, n0 = nt * 128;
    const unsigned short* Ap = P + (size_t)b * TT * TT + (size_t)t0 * TT;
    const unsigned short* Bp = vbT + ((size_t)b * DD + n0) * TT;
    int kend = (mt + 1) * 128;
    GEMM_CORE(Ap, TT, Bp, TT, 0, kend)
    int L = input_len[b];
#pragma unroll
    for (int im = 0; im < 4; im++) {
        int tbase = t0 + wm + im * 16 + quad * 4;
#pragma unroll
        for (int r = 0; r < 4; r++) {
            int t = tbase + r;
            float denom = rowsum[b * TT + t];
            float inv = 1.f / denom;
            bool valid = (t < L);
#pragma unroll
            for (int in = 0; in < 4; in++) {
                int n = n0 + wn + in * 16 + lm;
                float o = valid ? acc[im][in][r] * inv : 0.f;
                out[((size_t)b * TT + t) * DD + n] = o;
            }
        }
    }
}

// ---------------- launch ----------------
extern "C" void kernel_launch(void* const* d_in, const int* in_sizes, int n_in,
                              void* d_out, int out_size, void* d_ws, size_t ws_size,
                              hipStream_t stream) {
    const float* query = (const float*)d_in[0];
    const float* value = (const float*)d_in[1];
    const float* aux   = (const float*)d_in[2];
    const int*   ilen  = (const int*)d_in[3];
    const float* Wq    = (const float*)d_in[4];
    const float* bq    = (const float*)d_in[5];
    const float* Wqg   = (const float*)d_in[6];
    const float* bqg   = (const float*)d_in[7];
    const float* aq    = (const float*)d_in[8];
    const float* gq    = (const float*)d_in[9];
    const float* betaq = (const float*)d_in[10];
    const float* Wkg   = (const float*)d_in[11];
    const float* bkg   = (const float*)d_in[12];
    const float* ak    = (const float*)d_in[13];
    const float* gk    = (const float*)d_in[14];
    const float* betak = (const float*)d_in[15];
    const float* Wvg   = (const float*)d_in[16];
    const float* bvg   = (const float*)d_in[17];
    const float* av    = (const float*)d_in[18];
    const float* gv    = (const float*)d_in[19];
    const float* betav = (const float*)d_in[20];
    const float* Wsig  = (const float*)d_in[21];
    const float* bsig  = (const float*)d_in[22];
    const float* Wtan  = (const float*)d_in[23];
    const float* btan  = (const float*)d_in[24];

    char* ws = (char*)d_ws;
    float* qgate          = (float*)(ws + 0);          // 16 KB
    float* kgate          = (float*)(ws + 16384);      // 16 KB
    float* vgate          = (float*)(ws + 32768);      // 16 KB
    float* rowsum         = (float*)(ws + 49152);      // 64 KB
    unsigned short* Wqb   = (unsigned short*)(ws + 114688);    // 512 KB
    unsigned short* queryb= (unsigned short*)(ws + 638976);    // 16 MB
    unsigned short* qb    = (unsigned short*)(ws + 17416192);  // 16 MB
    unsigned short* kb    = (unsigned short*)(ws + 34193408);  // 16 MB
    unsigned short* vbT   = (unsigned short*)(ws + 50970624);  // 16 MB
    unsigned short* P     = (unsigned short*)(ws + 67747840);  // 64 MB  -> total ~128.6 MB
    // gate scratch overlays the P region (P is written only later, in scores_kernel)
    float* hbuf           = (float*)(ws + 67747840);           // 48 KB
    float* vg             = (float*)(ws + 67747840 + 49152);   // 16 KB

    hipMemsetAsync(rowsum, 0, BB * TT * sizeof(float), stream);

    gates_mv1<<<384, 256, 0, stream>>>(aux, Wqg, bqg, aq, Wkg, bkg, ak, Wvg, bvg, av, hbuf);
    gates_norm<<<24, 512, 0, stream>>>(hbuf, gq, betaq, gk, betak, gv, betav,
                                       qgate, kgate, vg);
    gates_mv2<<<128, 256, 0, stream>>>(vg, Wsig, bsig, Wtan, btan, vgate);

    prep_kernel<<<(BB * TT * DD / 4) / 256, 256, 0, stream>>>(query, queryb);
    wconv_kernel<<<(DD * DD / 4) / 256, 256, 0, stream>>>(Wq, Wqb);
    vk_kernel<<<dim3(TT / 32, DD / 32, BB), dim3(32, 8), 0, stream>>>(value, kgate, vgate, kb, vbT);
    qgemm_kernel<<<dim3((BB * TT) / 128, DD / 128), 256, 0, stream>>>(queryb, Wqb, bq, qgate, qb);
    scores_kernel<<<dim3(136, 1, BB), 256, 0, stream>>>(qb, kb, P, rowsum);
    out_kernel<<<dim3(DD / 128, TT / 128, BB), 256, 0, stream>>>(P, vbT, rowsum, ilen, (float*)d_out);
}